// Round 1
// baseline (208.637 us; speedup 1.0000x reference)
//
#include <hip/hip_runtime.h>
#include <hip/hip_bf16.h>

// DilatedMSA round 6: fp32 inputs, 3 kernels.
//  K0 convw: W fp32 -> bf16 (scratch in d_out tail, overwritten by attn).
//  K1 prep:  Q/K -> [blh][g][c'] (Q pre-scaled), V^T -> [blh][c'][g].
//            Epilogue via LDS (wb reuse) -> fully coalesced uint4 stores.
//  K2 attn:  NO K/V LDS staging (K/V are L2/L3-resident, block-private ->
//            fragments loaded direct from global). Per-wave 32-query tile,
//            grid (512,2,2), zero barriers, 16 waves/CU (VGPR-limited).

typedef __bf16 bf16x8 __attribute__((ext_vector_type(8)));
typedef float  f32x4  __attribute__((ext_vector_type(4)));

#define MFMA16(a, b, c) __builtin_amdgcn_mfma_f32_16x16x32_bf16((a), (b), (c), 0, 0, 0)

namespace dmsa {

constexpr int G  = 256;    // tokens per (b,l)
constexpr int C  = 128;    // channels
constexpr int HD = 64;     // head dim
// fold log2(e)/sqrt(128) into Q at prep time -> attn does exp2(s) directly
constexpr float QSCALE = 1.4426950408889634f * 0.08838834764831845f;

__device__ __forceinline__ unsigned pack2(float a, float b) {
    union { __hip_bfloat162 h; unsigned u; } c;
    c.h = __float22bfloat162_rn(make_float2(a, b));   // v_cvt_pk_bf16_f32
    return c.u;
}
__device__ __forceinline__ uint2 pack4(float a, float b, float c, float d) {
    uint2 r; r.x = pack2(a, b); r.y = pack2(c, d); return r;
}
__device__ __forceinline__ uint4 pack8(const float* p) {
    uint4 r;
    r.x = pack2(p[0], p[1]); r.y = pack2(p[2], p[3]);
    r.z = pack2(p[4], p[5]); r.w = pack2(p[6], p[7]);
    return r;
}
__device__ __forceinline__ bf16x8 lds8(const ushort* p) { return *(const bf16x8*)p; }
__device__ __forceinline__ bf16x8 ldg8(const ushort* p) { return *(const bf16x8*)p; }

// ---------------------------------------------------------------------------
// K0: W [384][128] fp32 -> bf16.
// ---------------------------------------------------------------------------
__global__ void convw(const float* __restrict__ W, ushort* __restrict__ wbf) {
    int t = blockIdx.x * 256 + threadIdx.x;      // 6144 threads * 8 = 49152
    float tmp[8];
    const float* p = W + (size_t)t * 8;
    *(float4*)tmp       = *(const float4*)p;
    *(float4*)(tmp + 4) = *(const float4*)(p + 4);
    *(uint4*)(wbf + (size_t)t * 8) = pack8(tmp);
}

// ---------------------------------------------------------------------------
// K1: per 64-token tile. grid 2048, block 256 (4 waves). LDS 52.2 KB.
// Q/K: y = W*x^T orientation (C/D row=ch, col=tok); V: x*W^T (row=tok, col=ch).
// Epilogue stages C/D into wb (dead after MFMA) then coalesced copy-out.
// ---------------------------------------------------------------------------
__global__ __launch_bounds__(256)
void prep(const float* __restrict__ x, const ushort* __restrict__ wbf,
          const float* __restrict__ bias, ushort* __restrict__ qb,
          ushort* __restrict__ kb, ushort* __restrict__ vt)
{
    __shared__ ushort xa[64 * 136];    // x tile bf16 [64 tok][128 +pad]
    __shared__ ushort wb[128 * 136];   // W chunk bf16; reused as epilogue stage

    const int tid = threadIdx.x, wv = tid >> 6, lane = tid & 63;
    const int l16 = lane & 15, quad = lane >> 4;
    const int mt = blockIdx.x, bl = mt >> 2, g0 = (mt & 3) * 64;

    // stage x tile fp32 -> bf16 (packed cvt)
    const float* xg = x + (size_t)mt * 64 * C;
    #pragma unroll
    for (int i = 0; i < 4; ++i) {
        int e = (tid + 256 * i) * 8, r = e >> 7, c = e & 127;
        float tmp[8];
        *(float4*)tmp       = *(const float4*)(xg + r * C + c);
        *(float4*)(tmp + 4) = *(const float4*)(xg + r * C + c + 4);
        *(uint4*)(xa + r * 136 + c) = pack8(tmp);
    }

    for (int nt = 0; nt < 3; ++nt) {
        __syncthreads();   // xa ready (nt=0) / previous copy-out readers done
        const ushort* wg = wbf + (size_t)nt * 128 * C;
        #pragma unroll
        for (int i = 0; i < 8; ++i) {
            int e = (tid + 256 * i) * 8, r = e >> 7, c = e & 127;
            *(uint4*)(wb + r * 136 + c) = *(const uint4*)(wg + r * C + c);
        }
        __syncthreads();

        const f32x4 z4 = {0.f, 0.f, 0.f, 0.f};
        if (nt < 2) {
            // A = W (m=ch, 8 tiles), B = x (n = tokens wv*16..+16)
            f32x4 acc[8];
            #pragma unroll
            for (int m = 0; m < 8; ++m) acc[m] = z4;
            #pragma unroll
            for (int kk = 0; kk < 4; ++kk) {
                bf16x8 b = lds8(xa + (wv * 16 + l16) * 136 + kk * 32 + quad * 8);
                #pragma unroll
                for (int m = 0; m < 8; ++m) {
                    bf16x8 a = lds8(wb + (m * 16 + l16) * 136 + kk * 32 + quad * 8);
                    acc[m] = MFMA16(a, b, acc[m]);
                }
            }
            __syncthreads();   // all wb MFMA reads done -> reuse wb as stage

            // stage[tok][ch] (stride 136): row=tok(l16+wv*16), 4 consecutive ch
            const float scale = (nt == 0) ? QSCALE : 1.0f;
            #pragma unroll
            for (int m = 0; m < 8; ++m) {
                int ch = m * 16 + quad * 4;
                float4 bs = *(const float4*)(bias + nt * C + ch);
                *(uint2*)(wb + (wv * 16 + l16) * 136 + ch) =
                    pack4((acc[m][0] + bs.x) * scale, (acc[m][1] + bs.y) * scale,
                          (acc[m][2] + bs.z) * scale, (acc[m][3] + bs.w) * scale);
            }
            __syncthreads();   // stage complete

            // copy-out per head: flat-contiguous 8 KB each, 16 B/lane
            ushort* dst0 = (nt == 0) ? qb : kb;
            #pragma unroll
            for (int h = 0; h < 2; ++h) {
                ushort* dsth = dst0 + ((size_t)(bl * 2 + h) * G + g0) * HD;
                #pragma unroll
                for (int j = 0; j < 2; ++j) {
                    int f = tid + 256 * j;            // 0..511
                    int tok = f >> 3, cc = (f & 7) * 8;
                    *(uint4*)(dsth + tok * HD + cc) =
                        *(const uint4*)(wb + tok * 136 + h * 64 + cc);
                }
            }
        } else {
            // V: A = x (m = tok, 4 tiles), B = W (n = ch wv*32..+32, 2 tiles)
            f32x4 acc[4][2];
            #pragma unroll
            for (int m = 0; m < 4; ++m)
                #pragma unroll
                for (int n = 0; n < 2; ++n) acc[m][n] = z4;
            #pragma unroll
            for (int kk = 0; kk < 4; ++kk) {
                bf16x8 a[4], b[2];
                #pragma unroll
                for (int m = 0; m < 4; ++m)
                    a[m] = lds8(xa + (m * 16 + l16) * 136 + kk * 32 + quad * 8);
                #pragma unroll
                for (int n = 0; n < 2; ++n)
                    b[n] = lds8(wb + (wv * 32 + n * 16 + l16) * 136 + kk * 32 + quad * 8);
                #pragma unroll
                for (int m = 0; m < 4; ++m)
                    #pragma unroll
                    for (int n = 0; n < 2; ++n)
                        acc[m][n] = MFMA16(a[m], b[n], acc[m][n]);
            }
            __syncthreads();   // wb reads done

            // stage[ch][tok] (stride 136): C/D row=tok (4 consecutive), col=ch
            #pragma unroll
            for (int n = 0; n < 2; ++n) {
                int ch = wv * 32 + n * 16 + l16;
                float bv = bias[2 * C + ch];
                #pragma unroll
                for (int m = 0; m < 4; ++m) {
                    int tokb = m * 16 + quad * 4;
                    *(uint2*)(wb + ch * 136 + tokb) =
                        pack4(acc[m][n][0] + bv, acc[m][n][1] + bv,
                              acc[m][n][2] + bv, acc[m][n][3] + bv);
                }
            }
            __syncthreads();

            // copy-out: 128 rows(ch) x 128 B; 4 lanes per row-segment
            #pragma unroll
            for (int j = 0; j < 4; ++j) {
                int f = tid + 256 * j;                // 0..1023
                int ch = f >> 3, gg = (f & 7) * 8;
                int h = ch >> 6, cp = ch & 63;
                *(uint4*)(vt + ((size_t)(bl * 2 + h) * HD + cp) * G + g0 + gg) =
                    *(const uint4*)(wb + ch * 136 + gg);
            }
        }
    }
}

// ---------------------------------------------------------------------------
// K2: attention. grid (512, 2, 2) = (bl, head, query-half), block 256 (4 waves).
// K/V fragments read DIRECT from global (L2/L3-resident, block-private data —
// LDS staging was pure overhead and capped occupancy at 2 blocks/CU).
// Wave wv owns g_q [qh*128 + wv*32, +32). Only LDS: per-wave P buffer (10 KB).
// Zero barriers. __launch_bounds__(256,4): 128-VGPR cap -> 16 waves/CU.
// ---------------------------------------------------------------------------
__global__ __launch_bounds__(256, 4)
void attn(const ushort* __restrict__ qb, const ushort* __restrict__ kb,
          const ushort* __restrict__ vt, float* __restrict__ out)
{
    __shared__ ushort pt[4 * 32 * 40];  // per-wave P [32 g_q][32 g_k +pad]

    const int tid = threadIdx.x, wv = tid >> 6, lane = tid & 63;
    const int l16 = lane & 15, quad = lane >> 4;
    const int bl = blockIdx.x, h = blockIdx.y, qh = blockIdx.z;

    const size_t blh = (size_t)(bl * 2 + h);
    const ushort* q = qb + blh * G * HD;
    const ushort* k = kb + blh * G * HD;
    const ushort* v = vt + blh * HD * G;
    ushort* ptw = pt + wv * (32 * 40);

    const int gq0 = qh * 128 + wv * 32;

    // Q B-fragments (held across the whole loop): B[n=g_q=l16][k=c'=quad*8+j]
    bf16x8 qf[2][2];
    #pragma unroll
    for (int ni = 0; ni < 2; ++ni)
        #pragma unroll
        for (int kk = 0; kk < 2; ++kk)
            qf[ni][kk] = ldg8(q + (size_t)(gq0 + ni * 16 + l16) * HD
                              + kk * 32 + quad * 8);

    const f32x4 z4 = {0.f, 0.f, 0.f, 0.f};
    float lacc[2] = {0.f, 0.f};
    f32x4 oacc[4][2];
    #pragma unroll
    for (int mi = 0; mi < 4; ++mi)
        #pragma unroll
        for (int ni = 0; ni < 2; ++ni) oacc[mi][ni] = z4;

    #pragma unroll 2
    for (int sub = 0; sub < 8; ++sub) {
        const int g0 = sub * 32;   // 32-key strip

        // K fragments direct from global: A[m=g_k][k=c']
        bf16x8 kf[2][2];
        #pragma unroll
        for (int kk = 0; kk < 2; ++kk)
            #pragma unroll
            for (int mi = 0; mi < 2; ++mi)
                kf[kk][mi] = ldg8(k + (size_t)(g0 + mi * 16 + l16) * HD
                                  + kk * 32 + quad * 8);

        // S^T [32 g_k][32 g_q]: A=K (m=g_k), B=Q (n=g_q), K-dim=c'
        f32x4 s[2][2];
        #pragma unroll
        for (int mi = 0; mi < 2; ++mi)
            #pragma unroll
            for (int ni = 0; ni < 2; ++ni) s[mi][ni] = z4;

        #pragma unroll
        for (int kk = 0; kk < 2; ++kk)
            #pragma unroll
            for (int mi = 0; mi < 2; ++mi)
                #pragma unroll
                for (int ni = 0; ni < 2; ++ni)
                    s[mi][ni] = MFMA16(kf[kk][mi], qf[ni][kk], s[mi][ni]);

        // issue V fragments now: latency hides under the softmax VALU block
        bf16x8 vf[4];
        #pragma unroll
        for (int mi = 0; mi < 4; ++mi)
            vf[mi] = ldg8(v + (size_t)(mi * 16 + l16) * G + g0 + quad * 8);

        // single-pass softmax: p = exp2(s) (scale folded into Q; |s| small)
        #pragma unroll
        for (int mi = 0; mi < 2; ++mi)
            #pragma unroll
            for (int ni = 0; ni < 2; ++ni) {
                #pragma unroll
                for (int r = 0; r < 4; ++r) {
                    float p = exp2f(s[mi][ni][r]);
                    s[mi][ni][r] = p;
                    lacc[ni] += p;
                }
                *(uint2*)(ptw + (ni * 16 + l16) * 40 + mi * 16 + quad * 4) =
                    pack4(s[mi][ni][0], s[mi][ni][1], s[mi][ni][2], s[mi][ni][3]);
            }

        // O^T += V^T * P^T (wave-local pt: lgkmcnt ordering, no barrier)
        bf16x8 pf[2];
        #pragma unroll
        for (int ni = 0; ni < 2; ++ni)
            pf[ni] = lds8(ptw + (ni * 16 + l16) * 40 + quad * 8);
        #pragma unroll
        for (int mi = 0; mi < 4; ++mi)
            #pragma unroll
            for (int ni = 0; ni < 2; ++ni)
                oacc[mi][ni] = MFMA16(vf[mi], pf[ni], oacc[mi][ni]);
    }

    // epilogue: out[bl, g_q, h*64+c']; C/D row = c' (quad*4+r +16mi), col = g_q
    float* og = out + (size_t)bl * G * C + h * HD;
    #pragma unroll
    for (int ni = 0; ni < 2; ++ni) {
        float l = lacc[ni];
        l += __shfl_xor(l, 16);
        l += __shfl_xor(l, 32);
        float inv = 1.0f / l;
        int g = gq0 + ni * 16 + l16;
        #pragma unroll
        for (int mi = 0; mi < 4; ++mi) {
            float4 st;
            st.x = oacc[mi][ni][0] * inv; st.y = oacc[mi][ni][1] * inv;
            st.z = oacc[mi][ni][2] * inv; st.w = oacc[mi][ni][3] * inv;
            *(float4*)(og + (size_t)g * C + mi * 16 + quad * 4) = st;
        }
    }
}

} // namespace dmsa

extern "C" void kernel_launch(void* const* d_in, const int* in_sizes, int n_in,
                              void* d_out, int out_size, void* d_ws, size_t ws_size,
                              hipStream_t stream) {
    (void)in_sizes; (void)n_in; (void)out_size;

    const size_t SEG = (size_t)1024 * 256 * 64;          // els per buffer
    if (ws_size < 3 * SEG * 2) return;                   // 100.66 MB needed

    const float* x    = (const float*)d_in[0];
    const float* W    = (const float*)d_in[1];
    const float* bias = (const float*)d_in[2];
    float* out = (float*)d_out;

    ushort* qb = (ushort*)d_ws;
    ushort* kb = qb + SEG;
    ushort* vt = kb + SEG;
    // W-bf16 scratch in d_out's tail (128 KB before end); attn overwrites later.
    ushort* wbf = (ushort*)((char*)d_out + ((size_t)16777216 * 4 - 131072));

    dmsa::convw<<<dim3(24), dim3(256), 0, stream>>>(W, wbf);
    dmsa::prep<<<dim3(2048), dim3(256), 0, stream>>>(x, wbf, bias, qb, kb, vt);
    dmsa::attn<<<dim3(512, 2, 2), dim3(256), 0, stream>>>(qb, kb, vt, out);
}